// Round 9
// baseline (267.467 us; speedup 1.0000x reference)
//
#include <hip/hip_runtime.h>

#define BB 16
#define MM 32
#define LH 128
#define NSTEPS 15          // K-1
#define SSTR 136
#define NBLK 256           // 2 rows per block, 512 threads (8 waves)
#define FSTR 32            // flag stride in ints (128 B apart)
#define SIDX(row,pxi,ch) (((row)*34 + (pxi))*SSTR + (ch))

typedef __bf16  bf16x8  __attribute__((ext_vector_type(8)));
typedef float   floatx4 __attribute__((ext_vector_type(4)));
typedef unsigned long long ull;

__device__ __forceinline__ float sigm(float x){ return 1.f/(1.f+__expf(-x)); }
__device__ __forceinline__ float tanh_f(float x){ return 1.f - 2.f/(__expf(2.f*x)+1.f); }

__device__ __forceinline__ unsigned short f2bf(float x){
  union { float f; unsigned u; } v; v.f = x;
  unsigned r = v.u + 0x7FFFu + ((v.u >> 16) & 1u);   // RNE
  return (unsigned short)(r >> 16);
}
__device__ __forceinline__ float bf2f(unsigned short u){
  union { unsigned u2; float f; } v; v.u2 = ((unsigned)u) << 16;
  return v.f;
}

// relaxed device-scope ops: complete at coherent point, no L2 wb/inv storms
__device__ __forceinline__ void st_dev(ull* p, ull v){
  __hip_atomic_store(p, v, __ATOMIC_RELAXED, __HIP_MEMORY_SCOPE_AGENT);
}
__device__ __forceinline__ ull ld_dev(ull* p){
  return __hip_atomic_load(p, __ATOMIC_RELAXED, __HIP_MEMORY_SCOPE_AGENT);
}
// poison-safe relaxed spin (0xAAAAAAAA == far behind under signed diff)
__device__ __forceinline__ void wait_flag(int* f, int target){
  while ((int)(__hip_atomic_load(f, __ATOMIC_RELAXED, __HIP_MEMORY_SCOPE_AGENT) - target) < 0){
    __builtin_amdgcn_s_sleep(1);
  }
}
__device__ __forceinline__ void set_flag(int* f, int v){
  // callers __syncthreads() first => vmcnt(0) drained => prior st_dev visible
  __hip_atomic_store(f, v, __ATOMIC_RELAXED, __HIP_MEMORY_SCOPE_AGENT);
}

// h exchange buffers use [global_row][ch][px4] b64-chunk layout:
// chunk index = grow*1024 + ch*8 + px4, holding h[px4*4..px4*4+3][ch].
__global__ __launch_bounds__(512, 2) void k_mega(
    const float* __restrict__ mp,   const float* __restrict__ gl,
    const float* __restrict__ W_hid,const float* __restrict__ b_hid,
    const float* __restrict__ W_h0, const float* __restrict__ b_h0,
    const float* __restrict__ W_c0, const float* __restrict__ b_c0,
    const float* __restrict__ Wf,   const float* __restrict__ bfs,
    const float* __restrict__ wih,  const float* __restrict__ bih,
    const float* __restrict__ Whh,  const float* __restrict__ bhh,
    const float* __restrict__ wpol,
    unsigned short* __restrict__ hA, unsigned short* __restrict__ hB,
    unsigned short* __restrict__ hidb,
    unsigned short* __restrict__ wc0, unsigned short* __restrict__ wc1,
    unsigned short* __restrict__ whhf, float* __restrict__ bsum,
    int* __restrict__ flags, float* __restrict__ out)
{
  __shared__ __attribute__((aligned(16))) unsigned short sH[4*34*SSTR]; // 37 KB
  __shared__ float sWf[9*LH];
  __shared__ float sInp[64];

  int t = threadIdx.x, blk = blockIdx.x;
  int pair = blk & 15, b = blk >> 4;
  int y0 = pair*2;          // first image row of the pair
  int r0 = blk*2;           // global row
  int p0 = r0*MM;           // global pixel base (64-px strip)
  int wave = t >> 6, l = t & 63, m16 = l & 15, quad = l >> 4;
  bool hasL = (pair > 0), hasR = (pair < 15);
  int ch = wave*16 + m16;   // this wave's 16-ch tile (per gate / per conv out)

  // ---- phase P: weight prep into fragment-linear bf16 -------------------
  for (int c = blk*512 + t; c < 90368; c += NBLK*512){
    if (c < 73728){
      int which = (c >= 36864) ? 1 : 0;
      int cc = which ? c - 36864 : c;
      int i2 = cc*4, frag = i2 >> 9, rem = i2 & 511, ll = rem >> 3, e0 = rem & 7;
      int kk = frag >> 5, ct = (frag >> 2) & 7, kc = frag & 3;
      int co = ct*16 + (ll & 15), ci0 = kc*32 + ((ll >> 4) << 3) + e0;
      const float* src = which ? W_c0 : W_h0;
      ull v = 0;
      #pragma unroll
      for (int j=0;j<4;j++) v |= (ull)f2bf(src[(kk<<14) + (ci0+j)*128 + co]) << (16*j);
      st_dev((ull*)(which ? wc1 : wc0) + cc, v);
    } else if (c < 90112){
      int cc = c - 73728;
      int i2 = cc*4, frag = i2 >> 9, rem = i2 & 511, ll = rem >> 3, e0 = rem & 7;
      int q = frag >> 5, ct = (frag >> 2) & 7, kc = frag & 3;
      int rw = q*128 + ct*16 + (ll & 15), col = kc*32 + ((ll >> 4) << 3) + e0;
      const float* s4 = Whh + rw*128 + col;
      ull v = 0;
      #pragma unroll
      for (int j=0;j<4;j++) v |= (ull)f2bf(s4[j]) << (16*j);
      st_dev((ull*)whhf + cc, v);
    } else {
      int cc = c - 90112; int j = cc*2;
      union { float f[2]; ull u; } pv;
      pv.f[0] = bih[j] + bhh[j]; pv.f[1] = bih[j+1] + bhh[j+1];
      st_dev((ull*)bsum + cc, pv.u);
    }
  }
  for (int id = t; id < 9*LH; id += 512) sWf[id] = Wf[id];

  // ---- phase H: hid for own 2 rows -> LDS temp -> write-through ---------
  {
    int hch = t & 127, g = t >> 7;        // g in 0..3
    int rr = g >> 1, xh = (g & 1)*16;
    int y = y0 + rr;
    for (int i = 0; i < 16; i++){
      int x = xh + i;
      float acc = b_hid[hch];
      #pragma unroll
      for (int ky=0; ky<3; ky++){
        int yy = y + ky - 1; if (yy < 0 || yy >= MM) continue;
        #pragma unroll
        for (int kx=0; kx<3; kx++){
          int xx = x + kx - 1; if (xx < 0 || xx >= MM) continue;
          int gi = (b*MM + yy)*MM + xx;
          int wb = ((ky*3+kx)*2)*LH + hch;
          acc += mp[gi] * W_hid[wb] + gl[gi] * W_hid[wb + LH];
        }
      }
      sH[(rr*32 + x)*128 + hch] = f2bf(acc);
    }
  }
  __syncthreads();
  #pragma unroll
  for (int j=0;j<4;j++){
    int chunk = j*512 + t;                // 2048 chunks = 2 rows, [px][ch] linear
    st_dev((ull*)hidb + p0*32 + chunk, *(ull*)&sH[chunk*4]);
  }
  __syncthreads();
  if (t == 0) set_flag(&flags[blk*FSTR], 1);
  if (t < NBLK) wait_flag(&flags[t*FSTR], 1);   // full grid
  __syncthreads();

  // ---- phase C: stage 4 hid rows (halo-padded) --------------------------
  #pragma unroll
  for (int j=0;j<8;j++){
    int chunk = j*512 + t;                // 4096 chunks = 4 rows
    int k = chunk >> 10, w = chunk & 1023, px = w >> 5, c4 = w & 31;
    int iy = y0 - 1 + k;
    ull v = 0;
    if (iy >= 0 && iy < MM) v = ld_dev((ull*)hidb + (((b*MM + iy)*MM) + px)*32 + c4);
    *(ull*)&sH[SIDX(k, px+1, c4*4)] = v;
  }
  if (t < 256){
    int k = t >> 6, col = ((t >> 5) & 1) ? 33 : 0, c4 = t & 31;
    *(ull*)&sH[SIDX(k, col, c4*4)] = 0;
  }
  __syncthreads();

  // ---- h0 & c0 convs: M=64 px, this wave's 16 out-ch --------------------
  float c_reg[4][4];        // [mt][r] — persists across all steps
  {
    floatx4 acch[4], accc[4];
    #pragma unroll
    for (int mt=0;mt<4;mt++){ acch[mt] = (floatx4){0.f,0.f,0.f,0.f};
                              accc[mt] = (floatx4){0.f,0.f,0.f,0.f}; }
    #pragma unroll
    for (int kk=0; kk<9; kk++){
      int ky = kk/3, kx = kk%3;
      #pragma unroll
      for (int kc=0; kc<4; kc++){
        int frag = ((kk*8 + wave)*4 + kc);
        bf16x8 b0 = *(const bf16x8*)(wc0 + (frag << 9) + l*8);
        bf16x8 b1 = *(const bf16x8*)(wc1 + (frag << 9) + l*8);
        #pragma unroll
        for (int mt=0; mt<4; mt++){
          bf16x8 a = *(const bf16x8*)&sH[SIDX((mt>>1)+ky, m16 + (mt&1)*16 + kx, kc*32 + quad*8)];
          acch[mt] = __builtin_amdgcn_mfma_f32_16x16x32_bf16(a, b0, acch[mt], 0,0,0);
          accc[mt] = __builtin_amdgcn_mfma_f32_16x16x32_bf16(a, b1, accc[mt], 0,0,0);
        }
      }
    }
    __syncthreads();                      // all conv reads done
    float bh = b_h0[ch], bc = b_c0[ch];
    #pragma unroll
    for (int mt=0; mt<4; mt++)
      #pragma unroll
      for (int r=0; r<4; r++){
        int px = mt*16 + quad*4 + r;      // 0..63
        c_reg[mt][r] = accc[mt][r] + bc;
        sH[SIDX(1+(px>>5), (px&31)+1, ch)] = f2bf(acch[mt][r] + bh);
      }
  }
  __syncthreads();
  // publish h0 in [row][ch][px4] chunk layout
  #pragma unroll
  for (int j=0;j<4;j++){
    int c = j*512 + t;                    // 2048 chunks
    int r = c >> 10, w = c & 1023, ch2 = w >> 3, px4 = w & 7;
    ull v = 0;
    #pragma unroll
    for (int i=0;i<4;i++)
      v |= (ull)sH[SIDX(1+r, px4*4+1+i, ch2)] << (16*i);
    st_dev((ull*)hA + (size_t)(r0+r)*1024 + w, v);
  }
  // boundary zero halo rows 0/3 (stay zero forever at image edges)
  if (!hasL){
    #pragma unroll
    for (int j=0;j<2;j++){
      int chunk = j*512 + t;
      *(ull*)&sH[SIDX(0, (chunk>>5)+1, (chunk&31)*4)] = 0;
    }
  }
  if (!hasR){
    #pragma unroll
    for (int j=0;j<2;j++){
      int chunk = j*512 + t;
      *(ull*)&sH[SIDX(3, (chunk>>5)+1, (chunk&31)*4)] = 0;
    }
  }
  __syncthreads();                        // vmcnt drained
  if (t == 0) set_flag(&flags[blk*FSTR], 2);

  // W_hh^T fragments (this wave: 16 ch x 4 gates x 4 kc) + epilogue consts
  bf16x8 bfr[4][4];   // [q][kc] — 64 VGPRs, constant across steps
  #pragma unroll
  for (int q=0;q<4;q++)
    #pragma unroll
    for (int kc=0;kc<4;kc++){
      int frag = ((q*8 + wave)*4 + kc);
      bfr[q][kc] = *(const bf16x8*)(whhf + (frag << 9) + l*8);
    }
  float wv[4], bs[4];
  #pragma unroll
  for (int q=0;q<4;q++){ int g = q*128 + ch; wv[q] = wih[g]; bs[q] = bsum[g]; }
  float bf0 = bfs[0];
  unsigned short* hb[2] = {hA, hB};

  int wpx = t >> 3, ws8 = t & 7;          // wf-conv assignment
  int wpr = wpx >> 5, wxr = wpx & 31;
  int halo_ky = wpr ? 2 : 0;              // the one halo tap row for this px

  // ---- 15 LSTM steps ----------------------------------------------------
  for (int s = 0; s < NSTEPS; s++){
    if (t == 0 && hasL) wait_flag(&flags[(blk-1)*FSTR], 2+s);
    if (t == 1 && hasR) wait_flag(&flags[(blk+1)*FSTR], 2+s);
    __syncthreads();                      // S0: neighbor h_s published

    // issue halo loads (rows r0-1, r0+2) in [ch][px4] layout
    ull hv[4];
    #pragma unroll
    for (int j=0;j<4;j++){
      int c = j*512 + t;                  // 2048 chunks = 2 halo rows
      int rsel = c >> 10, w = c & 1023;
      bool ok = rsel ? hasR : hasL;
      hv[j] = 0;
      if (ok){
        int grow = r0 + (rsel ? 2 : -1);
        hv[j] = ld_dev((ull*)hb[s&1] + (size_t)grow*1024 + w);
      }
    }

    // gates GEMM on own rows (LDS rows 1,2) while halo loads are in flight
    floatx4 acc[4][4];    // [mt][q]
    #pragma unroll
    for (int mt=0;mt<4;mt++)
      #pragma unroll
      for (int q=0;q<4;q++) acc[mt][q] = (floatx4){0.f,0.f,0.f,0.f};
    #pragma unroll
    for (int kc=0; kc<4; kc++){
      bf16x8 a[4];
      #pragma unroll
      for (int mt=0;mt<4;mt++)
        a[mt] = *(const bf16x8*)&sH[SIDX(1+(mt>>1), m16 + (mt&1)*16 + 1, kc*32 + quad*8)];
      #pragma unroll
      for (int q=0; q<4; q++)
        #pragma unroll
        for (int mt=0; mt<4; mt++)
          acc[mt][q] = __builtin_amdgcn_mfma_f32_16x16x32_bf16(a[mt], bfr[q][kc], acc[mt][q], 0,0,0);
    }

    // wf conv, own-row taps (rows 1,2) — still covering halo latency
    float wfa = 0.f;
    #pragma unroll
    for (int ky=0; ky<3; ky++){
      if (ky == halo_ky) continue;        // that tap needs the halo row
      #pragma unroll
      for (int kx=0; kx<3; kx++){
        int base = SIDX(wpr + ky, wxr + kx, ws8*16);
        uint4 h0v = *(const uint4*)&sH[base];
        uint4 h1v = *(const uint4*)&sH[base + 8];
        const float* wp = sWf + (ky*3+kx)*LH + ws8*16;
        const unsigned short* hu = (const unsigned short*)&h0v;
        #pragma unroll
        for (int e=0;e<8;e++) wfa += bf2f(hu[e]) * wp[e];
        hu = (const unsigned short*)&h1v;
        #pragma unroll
        for (int e=0;e<8;e++) wfa += bf2f(hu[e]) * wp[8+e];
      }
    }

    // land halos in LDS rows 0/3 (transpose [ch][px4] -> [px][ch])
    #pragma unroll
    for (int j=0;j<4;j++){
      int c = j*512 + t;
      int rsel = c >> 10, w = c & 1023, ch2 = w >> 3, px4 = w & 7;
      bool ok = rsel ? hasR : hasL;
      if (ok){
        int ldsrow = rsel ? 3 : 0;
        #pragma unroll
        for (int i=0;i<4;i++)
          sH[SIDX(ldsrow, px4*4+1+i, ch2)] = (unsigned short)(hv[j] >> (16*i));
      }
    }
    __syncthreads();                      // S1: halos in LDS

    // wf halo taps (row 0 or 3)
    {
      int hrow = wpr ? 3 : 0;
      #pragma unroll
      for (int kx=0; kx<3; kx++){
        int base = SIDX(hrow, wxr + kx, ws8*16);
        uint4 h0v = *(const uint4*)&sH[base];
        uint4 h1v = *(const uint4*)&sH[base + 8];
        const float* wp = sWf + (halo_ky*3+kx)*LH + ws8*16;
        const unsigned short* hu = (const unsigned short*)&h0v;
        #pragma unroll
        for (int e=0;e<8;e++) wfa += bf2f(hu[e]) * wp[e];
        hu = (const unsigned short*)&h1v;
        #pragma unroll
        for (int e=0;e<8;e++) wfa += bf2f(hu[e]) * wp[8+e];
      }
      wfa += __shfl_xor(wfa, 1, 64);
      wfa += __shfl_xor(wfa, 2, 64);
      wfa += __shfl_xor(wfa, 4, 64);
      if (ws8 == 0) sInp[wpx] = wfa + bf0;
    }
    __syncthreads();                      // S2: sInp ready, row1/2 reads done

    // LSTM pointwise epilogue: h_{s+1} -> LDS rows 1,2 + st_dev from regs
    #pragma unroll
    for (int mt=0; mt<4; mt++){
      ull pack = 0;
      #pragma unroll
      for (int r=0; r<4; r++){
        int px = mt*16 + quad*4 + r;
        float iv = sInp[px];
        float pre0 = acc[mt][0][r] + iv*wv[0] + bs[0];
        float pre1 = acc[mt][1][r] + iv*wv[1] + bs[1];
        float pre2 = acc[mt][2][r] + iv*wv[2] + bs[2];
        float pre3 = acc[mt][3][r] + iv*wv[3] + bs[3];
        float ig = sigm(pre0), fg = sigm(pre1), gg = tanh_f(pre2), og = sigm(pre3);
        float cn = fg*c_reg[mt][r] + ig*gg;
        c_reg[mt][r] = cn;
        unsigned short hbf = f2bf(og * tanh_f(cn));
        sH[SIDX(1+(px>>5), (px&31)+1, ch)] = hbf;
        pack |= (ull)hbf << (16*r);
      }
      if (s < NSTEPS-1){
        int grow = r0 + (mt>>1);
        int px4 = (mt&1)*4 + quad;
        st_dev((ull*)hb[(s+1)&1] + (size_t)grow*1024 + ch*8 + px4, pack);
      }
    }
    __syncthreads();                      // S3: LDS h_{s+1} visible + vmcnt drained
    if (t == 0 && s < NSTEPS-1) set_flag(&flags[blk*FSTR], 3+s);
  }

  // ---- policy: logits + 4-way softmax from LDS rows 1,2 -----------------
  {
    int px = t >> 3, s8 = t & 7;
    int base = SIDX(1+(px>>5), (px&31)+1, s8*16);
    uint4 h0v = *(const uint4*)&sH[base];
    uint4 h1v = *(const uint4*)&sH[base + 8];
    float la[4] = {0.f,0.f,0.f,0.f};
    const unsigned short* hu = (const unsigned short*)&h0v;
    #pragma unroll
    for (int e=0;e<8;e++){
      int c = s8*16 + e; float hv2 = bf2f(hu[e]);
      const float* w4 = wpol + c*4;
      la[0]+=hv2*w4[0]; la[1]+=hv2*w4[1]; la[2]+=hv2*w4[2]; la[3]+=hv2*w4[3];
    }
    hu = (const unsigned short*)&h1v;
    #pragma unroll
    for (int e=0;e<8;e++){
      int c = s8*16 + 8 + e; float hv2 = bf2f(hu[e]);
      const float* w4 = wpol + c*4;
      la[0]+=hv2*w4[0]; la[1]+=hv2*w4[1]; la[2]+=hv2*w4[2]; la[3]+=hv2*w4[3];
    }
    #pragma unroll
    for (int a=0;a<4;a++){
      la[a] += __shfl_xor(la[a], 1, 64);
      la[a] += __shfl_xor(la[a], 2, 64);
      la[a] += __shfl_xor(la[a], 4, 64);
    }
    if (s8 == 0){
      int y = y0 + (px>>5), x = px & 31;
      float m = fmaxf(fmaxf(la[0],la[1]),fmaxf(la[2],la[3]));
      float e[4]; float sum = 0.f;
      #pragma unroll
      for (int a=0;a<4;a++){ e[a]=__expf(la[a]-m); sum+=e[a]; }
      float inv = 1.f/sum;
      #pragma unroll
      for (int a=0;a<4;a++){
        int o = ((b*4 + a)*MM + y)*MM + x;
        out[o] = la[a];
        out[65536 + o] = e[a]*inv;
      }
    }
  }
}

extern "C" void kernel_launch(void* const* d_in, const int* in_sizes, int n_in,
                              void* d_out, int out_size, void* d_ws, size_t ws_size,
                              hipStream_t stream){
  const float* mp    = (const float*)d_in[0];
  const float* gl    = (const float*)d_in[1];
  const float* W_hid = (const float*)d_in[2];
  const float* b_hid = (const float*)d_in[3];
  const float* W_h0  = (const float*)d_in[4];
  const float* b_h0  = (const float*)d_in[5];
  const float* W_c0  = (const float*)d_in[6];
  const float* b_c0  = (const float*)d_in[7];
  const float* W_f   = (const float*)d_in[8];
  const float* b_f   = (const float*)d_in[9];
  const float* W_ih  = (const float*)d_in[10];
  const float* b_ih  = (const float*)d_in[11];
  const float* W_hh  = (const float*)d_in[12];
  const float* b_hh  = (const float*)d_in[13];
  const float* W_pol = (const float*)d_in[14];
  float* out = (float*)d_out;

  char* ws = (char*)d_ws;
  unsigned short* hA    = (unsigned short*)ws;                          // 4 MB
  unsigned short* hB    = (unsigned short*)(ws + ((size_t) 4<<20));     // 4 MB
  unsigned short* hidb  = (unsigned short*)(ws + ((size_t) 8<<20));     // 4 MB
  unsigned short* whhf  = (unsigned short*)(ws + ((size_t)12<<20));     // 128 KB
  float*          bsum  = (float*)(ws + ((size_t)12<<20) + (128<<10));  // 4 KB
  unsigned short* wc0   = (unsigned short*)(ws + ((size_t)12<<20) + (132<<10)); // 288 KB
  unsigned short* wc1   = (unsigned short*)(ws + ((size_t)12<<20) + (420<<10)); // 288 KB
  int*            flags = (int*)(ws + ((size_t)12<<20) + (708<<10));    // 32 KB

  k_mega<<<NBLK, 512, 0, stream>>>(
      mp, gl, W_hid, b_hid, W_h0, b_h0, W_c0, b_c0, W_f, b_f,
      W_ih, b_ih, W_hh, b_hh, W_pol,
      hA, hB, hidb, wc0, wc1, whhf, bsum, flags, out);
}

// Round 10
// 253.759 us; speedup vs baseline: 1.0540x; 1.0540x over previous
//
#include <hip/hip_runtime.h>

#define BB 16
#define MM 32
#define LH 128
#define NSTEPS 15          // K-1
#define SSTR 136
#define NBLK 256           // 2 rows per block, 512 threads (8 waves)
#define FSTR 32            // flag stride in ints (128 B apart)
#define SIDX(row,pxi,ch) (((row)*34 + (pxi))*SSTR + (ch))

typedef __bf16  bf16x8  __attribute__((ext_vector_type(8)));
typedef float   floatx4 __attribute__((ext_vector_type(4)));
typedef unsigned long long ull;

__device__ __forceinline__ float sigm(float x){ return 1.f/(1.f+__expf(-x)); }
__device__ __forceinline__ float tanh_f(float x){ return 1.f - 2.f/(__expf(2.f*x)+1.f); }

__device__ __forceinline__ unsigned short f2bf(float x){
  union { float f; unsigned u; } v; v.f = x;
  unsigned r = v.u + 0x7FFFu + ((v.u >> 16) & 1u);   // RNE
  return (unsigned short)(r >> 16);
}
__device__ __forceinline__ float bf2f(unsigned short u){
  union { unsigned u2; float f; } v; v.u2 = ((unsigned)u) << 16;
  return v.f;
}

// relaxed device-scope ops: complete at coherent point, no L2 wb/inv storms
__device__ __forceinline__ void st_dev(ull* p, ull v){
  __hip_atomic_store(p, v, __ATOMIC_RELAXED, __HIP_MEMORY_SCOPE_AGENT);
}
__device__ __forceinline__ ull ld_dev(ull* p){
  return __hip_atomic_load(p, __ATOMIC_RELAXED, __HIP_MEMORY_SCOPE_AGENT);
}
// poison-safe relaxed spin (0xAAAAAAAA == far behind under signed diff)
__device__ __forceinline__ void wait_flag(int* f, int target){
  while ((int)(__hip_atomic_load(f, __ATOMIC_RELAXED, __HIP_MEMORY_SCOPE_AGENT) - target) < 0){
    __builtin_amdgcn_s_sleep(1);
  }
}
__device__ __forceinline__ void set_flag(int* f, int v){
  // callers __syncthreads() first => vmcnt(0) drained => prior st_dev visible
  __hip_atomic_store(f, v, __ATOMIC_RELAXED, __HIP_MEMORY_SCOPE_AGENT);
}

// h exchange buffers use [global_row][ch][px4] b64-chunk layout:
// chunk index = grow*1024 + ch*8 + px4, holding h[px4*4..px4*4+3][ch].
__global__ __launch_bounds__(512, 2) void k_mega(
    const float* __restrict__ mp,   const float* __restrict__ gl,
    const float* __restrict__ W_hid,const float* __restrict__ b_hid,
    const float* __restrict__ W_h0, const float* __restrict__ b_h0,
    const float* __restrict__ W_c0, const float* __restrict__ b_c0,
    const float* __restrict__ Wf,   const float* __restrict__ bfs,
    const float* __restrict__ wih,  const float* __restrict__ bih,
    const float* __restrict__ Whh,  const float* __restrict__ bhh,
    const float* __restrict__ wpol,
    unsigned short* __restrict__ hA, unsigned short* __restrict__ hB,
    unsigned short* __restrict__ hidb,
    unsigned short* __restrict__ wc0, unsigned short* __restrict__ wc1,
    unsigned short* __restrict__ whhf, float* __restrict__ bsum,
    unsigned short* __restrict__ wfbF,
    int* __restrict__ flags, float* __restrict__ out)
{
  __shared__ __attribute__((aligned(16))) unsigned short sH[4*34*SSTR]; // 37 KB
  __shared__ float sInp[64];

  int t = threadIdx.x, blk = blockIdx.x;
  int pair = blk & 15, b = blk >> 4;
  int y0 = pair*2;          // first image row of the pair
  int r0 = blk*2;           // global row
  int p0 = r0*MM;           // global pixel base (64-px strip)
  int wave = t >> 6, l = t & 63, m16 = l & 15, quad = l >> 4;
  bool hasL = (pair > 0), hasR = (pair < 15);
  int ch = wave*16 + m16;   // this wave's 16-ch tile (per gate / per conv out)

  // ---- phase P: weight prep into fragment-linear bf16 -------------------
  for (int c = blk*512 + t; c < 91904; c += NBLK*512){
    if (c < 73728){
      int which = (c >= 36864) ? 1 : 0;
      int cc = which ? c - 36864 : c;
      int i2 = cc*4, frag = i2 >> 9, rem = i2 & 511, ll = rem >> 3, e0 = rem & 7;
      int kk = frag >> 5, ct = (frag >> 2) & 7, kc = frag & 3;
      int co = ct*16 + (ll & 15), ci0 = kc*32 + ((ll >> 4) << 3) + e0;
      const float* src = which ? W_c0 : W_h0;
      ull v = 0;
      #pragma unroll
      for (int j=0;j<4;j++) v |= (ull)f2bf(src[(kk<<14) + (ci0+j)*128 + co]) << (16*j);
      st_dev((ull*)(which ? wc1 : wc0) + cc, v);
    } else if (c < 90112){
      int cc = c - 73728;
      int i2 = cc*4, frag = i2 >> 9, rem = i2 & 511, ll = rem >> 3, e0 = rem & 7;
      int q = frag >> 5, ct = (frag >> 2) & 7, kc = frag & 3;
      int rw = q*128 + ct*16 + (ll & 15), col = kc*32 + ((ll >> 4) << 3) + e0;
      const float* s4 = Whh + rw*128 + col;
      ull v = 0;
      #pragma unroll
      for (int j=0;j<4;j++) v |= (ull)f2bf(s4[j]) << (16*j);
      st_dev((ull*)whhf + cc, v);
    } else if (c < 90368){
      int cc = c - 90112; int j = cc*2;
      union { float f[2]; ull u; } pv;
      pv.f[0] = bih[j] + bhh[j]; pv.f[1] = bih[j+1] + bhh[j+1];
      st_dev((ull*)bsum + cc, pv.u);
    } else {
      // wf B-fragments: frag = ky*4+kc; cols 0..2 = Wf taps (kx), rest zero
      int cc = c - 90368;
      int i2 = cc*4, frag = i2 >> 9, rem = i2 & 511, ll = rem >> 3, e0 = rem & 7;
      int ky = frag >> 2, kc = frag & 3;
      int n = ll & 15, k0 = kc*32 + ((ll >> 4) << 3) + e0;
      ull v = 0;
      if (n < 3){
        #pragma unroll
        for (int j=0;j<4;j++) v |= (ull)f2bf(Wf[(ky*3 + n)*128 + k0 + j]) << (16*j);
      }
      st_dev((ull*)wfbF + cc, v);
    }
  }

  // ---- phase H: hid for own 2 rows -> LDS temp -> write-through ---------
  {
    int hch = t & 127, g = t >> 7;        // g in 0..3
    int rr = g >> 1, xh = (g & 1)*16;
    int y = y0 + rr;
    for (int i = 0; i < 16; i++){
      int x = xh + i;
      float acc = b_hid[hch];
      #pragma unroll
      for (int ky=0; ky<3; ky++){
        int yy = y + ky - 1; if (yy < 0 || yy >= MM) continue;
        #pragma unroll
        for (int kx=0; kx<3; kx++){
          int xx = x + kx - 1; if (xx < 0 || xx >= MM) continue;
          int gi = (b*MM + yy)*MM + xx;
          int wb = ((ky*3+kx)*2)*LH + hch;
          acc += mp[gi] * W_hid[wb] + gl[gi] * W_hid[wb + LH];
        }
      }
      sH[(rr*32 + x)*128 + hch] = f2bf(acc);
    }
  }
  __syncthreads();
  #pragma unroll
  for (int j=0;j<4;j++){
    int chunk = j*512 + t;                // 2048 chunks = 2 rows, [px][ch] linear
    st_dev((ull*)hidb + p0*32 + chunk, *(ull*)&sH[chunk*4]);
  }
  __syncthreads();
  if (t == 0) set_flag(&flags[blk*FSTR], 1);
  if (t < NBLK) wait_flag(&flags[t*FSTR], 1);   // full grid
  __syncthreads();

  // ---- phase C: stage 4 hid rows (halo-padded) --------------------------
  #pragma unroll
  for (int j=0;j<8;j++){
    int chunk = j*512 + t;                // 4096 chunks = 4 rows
    int k = chunk >> 10, w = chunk & 1023, px = w >> 5, c4 = w & 31;
    int iy = y0 - 1 + k;
    ull v = 0;
    if (iy >= 0 && iy < MM) v = ld_dev((ull*)hidb + (((b*MM + iy)*MM) + px)*32 + c4);
    *(ull*)&sH[SIDX(k, px+1, c4*4)] = v;
  }
  if (t < 256){
    int k = t >> 6, col = ((t >> 5) & 1) ? 33 : 0, c4 = t & 31;
    *(ull*)&sH[SIDX(k, col, c4*4)] = 0;
  }
  __syncthreads();

  // ---- h0 & c0 convs: M=64 px, this wave's 16 out-ch --------------------
  float c_reg[4][4];        // [mt][r] — persists across all steps
  {
    floatx4 acch[4], accc[4];
    #pragma unroll
    for (int mt=0;mt<4;mt++){ acch[mt] = (floatx4){0.f,0.f,0.f,0.f};
                              accc[mt] = (floatx4){0.f,0.f,0.f,0.f}; }
    #pragma unroll
    for (int kk=0; kk<9; kk++){
      int ky = kk/3, kx = kk%3;
      #pragma unroll
      for (int kc=0; kc<4; kc++){
        int frag = ((kk*8 + wave)*4 + kc);
        bf16x8 b0 = *(const bf16x8*)(wc0 + (frag << 9) + l*8);
        bf16x8 b1 = *(const bf16x8*)(wc1 + (frag << 9) + l*8);
        #pragma unroll
        for (int mt=0; mt<4; mt++){
          bf16x8 a = *(const bf16x8*)&sH[SIDX((mt>>1)+ky, m16 + (mt&1)*16 + kx, kc*32 + quad*8)];
          acch[mt] = __builtin_amdgcn_mfma_f32_16x16x32_bf16(a, b0, acch[mt], 0,0,0);
          accc[mt] = __builtin_amdgcn_mfma_f32_16x16x32_bf16(a, b1, accc[mt], 0,0,0);
        }
      }
    }
    __syncthreads();                      // all conv reads done
    float bh = b_h0[ch], bc = b_c0[ch];
    #pragma unroll
    for (int mt=0; mt<4; mt++)
      #pragma unroll
      for (int r=0; r<4; r++){
        int px = mt*16 + quad*4 + r;      // 0..63
        c_reg[mt][r] = accc[mt][r] + bc;
        sH[SIDX(1+(px>>5), (px&31)+1, ch)] = f2bf(acch[mt][r] + bh);
      }
  }
  __syncthreads();
  // publish h0 in [row][ch][px4] chunk layout
  #pragma unroll
  for (int j=0;j<4;j++){
    int c = j*512 + t;                    // 2048 chunks
    int r = c >> 10, w = c & 1023, ch2 = w >> 3, px4 = w & 7;
    ull v = 0;
    #pragma unroll
    for (int i=0;i<4;i++)
      v |= (ull)sH[SIDX(1+r, px4*4+1+i, ch2)] << (16*i);
    st_dev((ull*)hA + (size_t)(r0+r)*1024 + w, v);
  }
  // boundary zero halo rows 0/3 (stay zero forever at image edges)
  if (!hasL){
    #pragma unroll
    for (int j=0;j<2;j++){
      int chunk = j*512 + t;
      *(ull*)&sH[SIDX(0, (chunk>>5)+1, (chunk&31)*4)] = 0;
    }
  }
  if (!hasR){
    #pragma unroll
    for (int j=0;j<2;j++){
      int chunk = j*512 + t;
      *(ull*)&sH[SIDX(3, (chunk>>5)+1, (chunk&31)*4)] = 0;
    }
  }
  __syncthreads();                        // vmcnt drained
  if (t == 0) set_flag(&flags[blk*FSTR], 2);

  // W_hh^T fragments (this wave: 16 ch x 4 gates x 4 kc) + epilogue consts
  bf16x8 bfr[4][4];   // [q][kc] — 64 VGPRs, constant across steps
  #pragma unroll
  for (int q=0;q<4;q++)
    #pragma unroll
    for (int kc=0;kc<4;kc++){
      int frag = ((q*8 + wave)*4 + kc);
      bfr[q][kc] = *(const bf16x8*)(whhf + (frag << 9) + l*8);
    }
  // wf B-fragments for this wave's kc-half (3 ky x 2 kc)
  int mtw = wave & 3, kh = (wave >> 2) * 2;
  bf16x8 wfBr[3][2];
  #pragma unroll
  for (int ky=0;ky<3;ky++)
    #pragma unroll
    for (int kk2=0;kk2<2;kk2++)
      wfBr[ky][kk2] = *(const bf16x8*)(wfbF + (((ky*4 + kh + kk2) << 9) + l*8));
  float wv[4], bs[4];
  #pragma unroll
  for (int q=0;q<4;q++){ int g = q*128 + ch; wv[q] = wih[g]; bs[q] = bsum[g]; }
  float bf0 = bfs[0];
  unsigned short* hb[2] = {hA, hB};
  int Rrow = mtw >> 1, xhw = (mtw & 1) * 16;

  // ---- 15 LSTM steps ----------------------------------------------------
  for (int s = 0; s < NSTEPS; s++){
    if (t == 0 && hasL) wait_flag(&flags[(blk-1)*FSTR], 2+s);
    if (t == 1 && hasR) wait_flag(&flags[(blk+1)*FSTR], 2+s);
    __syncthreads();                      // S0: neighbor h_s published

    if (t < 64) sInp[t] = bf0;            // init gate-input accumulator

    // issue halo loads (rows r0-1, r0+2) in [ch][px4] layout
    ull hv[4];
    #pragma unroll
    for (int j=0;j<4;j++){
      int c = j*512 + t;                  // 2048 chunks = 2 halo rows
      int rsel = c >> 10, w = c & 1023;
      bool ok = rsel ? hasR : hasL;
      hv[j] = 0;
      if (ok){
        int grow = r0 + (rsel ? 2 : -1);
        hv[j] = ld_dev((ull*)hb[s&1] + (size_t)grow*1024 + w);
      }
    }

    // gates GEMM on own rows (LDS rows 1,2) while halo loads are in flight
    floatx4 acc[4][4];    // [mt][q]
    #pragma unroll
    for (int mt=0;mt<4;mt++)
      #pragma unroll
      for (int q=0;q<4;q++) acc[mt][q] = (floatx4){0.f,0.f,0.f,0.f};
    #pragma unroll
    for (int kc=0; kc<4; kc++){
      bf16x8 a[4];
      #pragma unroll
      for (int mt=0;mt<4;mt++)
        a[mt] = *(const bf16x8*)&sH[SIDX(1+(mt>>1), m16 + (mt&1)*16 + 1, kc*32 + quad*8)];
      #pragma unroll
      for (int q=0; q<4; q++)
        #pragma unroll
        for (int mt=0; mt<4; mt++)
          acc[mt][q] = __builtin_amdgcn_mfma_f32_16x16x32_bf16(a[mt], bfr[q][kc], acc[mt][q], 0,0,0);
    }

    // land halos in LDS rows 0/3 (transpose [ch][px4] -> [px][ch])
    #pragma unroll
    for (int j=0;j<4;j++){
      int c = j*512 + t;
      int rsel = c >> 10, w = c & 1023, ch2 = w >> 3, px4 = w & 7;
      bool ok = rsel ? hasR : hasL;
      if (ok){
        int ldsrow = rsel ? 3 : 0;
        #pragma unroll
        for (int i=0;i<4;i++)
          sH[SIDX(ldsrow, px4*4+1+i, ch2)] = (unsigned short)(hv[j] >> (16*i));
      }
    }
    __syncthreads();                      // S1: halos in LDS, sInp inited

    // wf conv via MFMA: P[x][kx] = sum_ky dot(h[Rrow+ky][x], Wf[ky][kx])
    // wave handles tile mtw, kc-half kh; ky-sum free via accumulation
    {
      floatx4 pacc = (floatx4){0.f,0.f,0.f,0.f};
      #pragma unroll
      for (int ky=0; ky<3; ky++){
        #pragma unroll
        for (int kk2=0; kk2<2; kk2++){
          int kc = kh + kk2;
          bf16x8 a = *(const bf16x8*)&sH[SIDX(Rrow+ky, xhw + m16 + 1, kc*32 + quad*8)];
          pacc = __builtin_amdgcn_mfma_f32_16x16x32_bf16(a, wfBr[ky][kk2], pacc, 0,0,0);
        }
      }
      if (m16 < 3){
        int dx = m16 - 1;
        #pragma unroll
        for (int r=0; r<4; r++){
          int px = mtw*16 + quad*4 + r;
          int x = px & 31;
          int xt = x + dx;
          if (xt >= 0 && xt < 32)
            atomicAdd(&sInp[(px & 32) + xt], pacc[r]);
        }
      }
    }
    __syncthreads();                      // S2: sInp complete, row reads done

    // LSTM pointwise epilogue: h_{s+1} -> LDS rows 1,2 + st_dev from regs
    #pragma unroll
    for (int mt=0; mt<4; mt++){
      ull pack = 0;
      #pragma unroll
      for (int r=0; r<4; r++){
        int px = mt*16 + quad*4 + r;
        float iv = sInp[px];
        float pre0 = acc[mt][0][r] + iv*wv[0] + bs[0];
        float pre1 = acc[mt][1][r] + iv*wv[1] + bs[1];
        float pre2 = acc[mt][2][r] + iv*wv[2] + bs[2];
        float pre3 = acc[mt][3][r] + iv*wv[3] + bs[3];
        float ig = sigm(pre0), fg = sigm(pre1), gg = tanh_f(pre2), og = sigm(pre3);
        float cn = fg*c_reg[mt][r] + ig*gg;
        c_reg[mt][r] = cn;
        unsigned short hbf = f2bf(og * tanh_f(cn));
        sH[SIDX(1+(px>>5), (px&31)+1, ch)] = hbf;
        pack |= (ull)hbf << (16*r);
      }
      if (s < NSTEPS-1){
        int grow = r0 + (mt>>1);
        int px4 = (mt&1)*4 + quad;
        st_dev((ull*)hb[(s+1)&1] + (size_t)grow*1024 + ch*8 + px4, pack);
      }
    }
    __syncthreads();                      // S3: LDS h_{s+1} visible + vmcnt drained
    if (t == 0 && s < NSTEPS-1) set_flag(&flags[blk*FSTR], 3+s);
  }

  // ---- policy: logits + 4-way softmax from LDS rows 1,2 -----------------
  {
    int px = t >> 3, s8 = t & 7;
    int base = SIDX(1+(px>>5), (px&31)+1, s8*16);
    uint4 h0v = *(const uint4*)&sH[base];
    uint4 h1v = *(const uint4*)&sH[base + 8];
    float la[4] = {0.f,0.f,0.f,0.f};
    const unsigned short* hu = (const unsigned short*)&h0v;
    #pragma unroll
    for (int e=0;e<8;e++){
      int c = s8*16 + e; float hv2 = bf2f(hu[e]);
      const float* w4 = wpol + c*4;
      la[0]+=hv2*w4[0]; la[1]+=hv2*w4[1]; la[2]+=hv2*w4[2]; la[3]+=hv2*w4[3];
    }
    hu = (const unsigned short*)&h1v;
    #pragma unroll
    for (int e=0;e<8;e++){
      int c = s8*16 + 8 + e; float hv2 = bf2f(hu[e]);
      const float* w4 = wpol + c*4;
      la[0]+=hv2*w4[0]; la[1]+=hv2*w4[1]; la[2]+=hv2*w4[2]; la[3]+=hv2*w4[3];
    }
    #pragma unroll
    for (int a=0;a<4;a++){
      la[a] += __shfl_xor(la[a], 1, 64);
      la[a] += __shfl_xor(la[a], 2, 64);
      la[a] += __shfl_xor(la[a], 4, 64);
    }
    if (s8 == 0){
      int y = y0 + (px>>5), x = px & 31;
      float m = fmaxf(fmaxf(la[0],la[1]),fmaxf(la[2],la[3]));
      float e[4]; float sum = 0.f;
      #pragma unroll
      for (int a=0;a<4;a++){ e[a]=__expf(la[a]-m); sum+=e[a]; }
      float inv = 1.f/sum;
      #pragma unroll
      for (int a=0;a<4;a++){
        int o = ((b*4 + a)*MM + y)*MM + x;
        out[o] = la[a];
        out[65536 + o] = e[a]*inv;
      }
    }
  }
}

extern "C" void kernel_launch(void* const* d_in, const int* in_sizes, int n_in,
                              void* d_out, int out_size, void* d_ws, size_t ws_size,
                              hipStream_t stream){
  const float* mp    = (const float*)d_in[0];
  const float* gl    = (const float*)d_in[1];
  const float* W_hid = (const float*)d_in[2];
  const float* b_hid = (const float*)d_in[3];
  const float* W_h0  = (const float*)d_in[4];
  const float* b_h0  = (const float*)d_in[5];
  const float* W_c0  = (const float*)d_in[6];
  const float* b_c0  = (const float*)d_in[7];
  const float* W_f   = (const float*)d_in[8];
  const float* b_f   = (const float*)d_in[9];
  const float* W_ih  = (const float*)d_in[10];
  const float* b_ih  = (const float*)d_in[11];
  const float* W_hh  = (const float*)d_in[12];
  const float* b_hh  = (const float*)d_in[13];
  const float* W_pol = (const float*)d_in[14];
  float* out = (float*)d_out;

  char* ws = (char*)d_ws;
  unsigned short* hA    = (unsigned short*)ws;                          // 4 MB
  unsigned short* hB    = (unsigned short*)(ws + ((size_t) 4<<20));     // 4 MB
  unsigned short* hidb  = (unsigned short*)(ws + ((size_t) 8<<20));     // 4 MB
  unsigned short* whhf  = (unsigned short*)(ws + ((size_t)12<<20));     // 128 KB
  float*          bsum  = (float*)(ws + ((size_t)12<<20) + (128<<10));  // 4 KB
  unsigned short* wc0   = (unsigned short*)(ws + ((size_t)12<<20) + (132<<10)); // 288 KB
  unsigned short* wc1   = (unsigned short*)(ws + ((size_t)12<<20) + (420<<10)); // 288 KB
  int*            flags = (int*)(ws + ((size_t)12<<20) + (708<<10));    // 32 KB
  unsigned short* wfbF  = (unsigned short*)(ws + ((size_t)12<<20) + (740<<10)); // 12 KB

  k_mega<<<NBLK, 512, 0, stream>>>(
      mp, gl, W_hid, b_hid, W_h0, b_h0, W_c0, b_c0, W_f, b_f,
      W_ih, b_ih, W_hh, b_hh, W_pol,
      hA, hB, hidb, wc0, wc1, whhf, bsum, wfbF, flags, out);
}